// Round 1
// baseline (1175.938 us; speedup 1.0000x reference)
//
#include <hip/hip_runtime.h>
#include <math.h>

#define N_NODES 10000
#define N_EDGES 320000
#define DIM     176
#define ATT     16
#define SH_HEADS 16
#define THH     4
#define NH      20          // SH_HEADS + TH
#define VD      11          // DIM / SH_HEADS
#define NSPH    16
#define ZDIM    16
#define RDIM    16
#define QK_W    (NH*ATT)    // 320
#define UI_W    (2*DIM)     // 352

// ---------------- helpers ----------------

__device__ __forceinline__ void sph16(float x, float y, float z, float* Y) {
    const float s3  = 1.7320508075688772f;   // sqrt(3)
    const float s15 = 3.872983346207417f;    // sqrt(15)
    const float c1  = 0.7905694150420949f;   // sqrt(5/8)
    const float c2  = 0.6123724356957945f;   // sqrt(3/8)
    float x2 = x*x, y2 = y*y, z2 = z*z;
    Y[0]  = 1.0f;
    Y[1]  = x;
    Y[2]  = y;
    Y[3]  = z;
    Y[4]  = s3 * x * y;
    Y[5]  = s3 * y * z;
    Y[6]  = 0.5f * (3.0f * z2 - 1.0f);
    Y[7]  = s3 * x * z;
    Y[8]  = 0.5f * s3 * (x2 - y2);
    Y[9]  = c1 * y * (3.0f * x2 - y2);
    Y[10] = s15 * x * y * z;
    Y[11] = c2 * y * (5.0f * z2 - 1.0f);
    Y[12] = 0.5f * z * (5.0f * z2 - 3.0f);
    Y[13] = c2 * x * (5.0f * z2 - 1.0f);
    Y[14] = 0.5f * s15 * z * (x2 - y2);
    Y[15] = c1 * x * (x2 - 3.0f * y2);
}

// divergence-free dynamic select from a 16-entry register array
__device__ __forceinline__ float sel16(const float* Y, int i) {
    float a0 = (i & 1) ? Y[1]  : Y[0];
    float a1 = (i & 1) ? Y[3]  : Y[2];
    float a2 = (i & 1) ? Y[5]  : Y[4];
    float a3 = (i & 1) ? Y[7]  : Y[6];
    float a4 = (i & 1) ? Y[9]  : Y[8];
    float a5 = (i & 1) ? Y[11] : Y[10];
    float a6 = (i & 1) ? Y[13] : Y[12];
    float a7 = (i & 1) ? Y[15] : Y[14];
    float b0 = (i & 2) ? a1 : a0;
    float b1 = (i & 2) ? a3 : a2;
    float b2 = (i & 2) ? a5 : a4;
    float b3 = (i & 2) ? a7 : a6;
    float c0 = (i & 4) ? b1 : b0;
    float c1 = (i & 4) ? b3 : b2;
    return (i & 8) ? c1 : c0;
}

// ---------------- CSR build ----------------

__global__ __launch_bounds__(256) void k_zero(int* deg) {
    int i = blockIdx.x * 256 + threadIdx.x;
    if (i < N_NODES) deg[i] = 0;
}

__global__ __launch_bounds__(256) void k_deg(const int* edst, int* deg) {
    int e = blockIdx.x * 256 + threadIdx.x;
    if (e < N_EDGES) atomicAdd(&deg[edst[e]], 1);
}

__global__ __launch_bounds__(1024) void k_scan(const int* deg, int* off, int* cursor) {
    __shared__ int sd[1024];
    __shared__ int carry;
    int tid = threadIdx.x;
    if (tid == 0) { off[0] = 0; carry = 0; }
    __syncthreads();
    for (int b0 = 0; b0 < N_NODES; b0 += 1024) {
        int v = (b0 + tid < N_NODES) ? deg[b0 + tid] : 0;
        sd[tid] = v;
        __syncthreads();
        for (int s = 1; s < 1024; s <<= 1) {
            int add = (tid >= s) ? sd[tid - s] : 0;
            __syncthreads();
            sd[tid] += add;
            __syncthreads();
        }
        int incl = sd[tid];
        if (b0 + tid < N_NODES) {
            off[b0 + tid + 1]  = carry + incl;
            cursor[b0 + tid]   = carry + incl - v;
        }
        __syncthreads();
        if (tid == 0) carry += sd[1023];
        __syncthreads();
    }
}

__global__ __launch_bounds__(256) void k_scatter(const int* edst, int* cursor, int* elist) {
    int e = blockIdx.x * 256 + threadIdx.x;
    if (e < N_EDGES) {
        int p = atomicAdd(&cursor[edst[e]], 1);
        elist[p] = e;
    }
}

// ---------------- node embedding: xi = LN(z_table[species] @ w_species) ----------------

__global__ __launch_bounds__(256) void k_node_init(const int* species, const float* z_table,
                                                   const float* wsp, float* xi) {
    __shared__ float zs[16 * ZDIM];
    __shared__ float yt[16 * DIM];
    __shared__ float red[256];
    __shared__ float mus[16], rstds[16];
    int base = blockIdx.x * 16;
    int tid  = threadIdx.x;
    { int n = tid >> 4, kk = tid & 15;
      zs[tid] = z_table[species[base + n] * ZDIM + kk]; }
    __syncthreads();
    int c = tid;
    if (c < DIM) {
        float acc[16];
        #pragma unroll
        for (int n = 0; n < 16; n++) acc[n] = 0.0f;
        for (int kk = 0; kk < ZDIM; kk++) {
            float w = wsp[kk * DIM + c];
            #pragma unroll
            for (int n = 0; n < 16; n++) acc[n] += zs[n * ZDIM + kk] * w;
        }
        #pragma unroll
        for (int n = 0; n < 16; n++) yt[n * DIM + c] = acc[n];
    }
    __syncthreads();
    { int n2 = tid >> 4, j = tid & 15;
      float s = 0.0f;
      for (int c2 = j; c2 < DIM; c2 += 16) s += yt[n2 * DIM + c2];
      red[tid] = s; }
    __syncthreads();
    if (tid < 16) { float s = 0; for (int j = 0; j < 16; j++) s += red[tid * 16 + j]; mus[tid] = s / (float)DIM; }
    __syncthreads();
    { int n2 = tid >> 4, j = tid & 15;
      float mu = mus[n2], s = 0.0f;
      for (int c2 = j; c2 < DIM; c2 += 16) { float d = yt[n2 * DIM + c2] - mu; s += d * d; }
      red[tid] = s; }
    __syncthreads();
    if (tid < 16) { float s = 0; for (int j = 0; j < 16; j++) s += red[tid * 16 + j]; rstds[tid] = rsqrtf(s / (float)DIM + 1e-6f); }
    __syncthreads();
    if (c < DIM) {
        #pragma unroll
        for (int n = 0; n < 16; n++)
            xi[(size_t)(base + n) * DIM + c] = (yt[n * DIM + c] - mus[n]) * rstds[n];
    }
}

// ---------------- q/k/v projection ----------------

__global__ __launch_bounds__(256) void k_qkv(const float* xi, const float* wq, const float* wk,
                                             const float* wv, float* qo, float* ko, float* vo) {
    __shared__ float xs[16 * DIM];
    int base = blockIdx.x * 16;
    int tid  = threadIdx.x;
    for (int idx = tid; idx < 16 * DIM; idx += 256) xs[idx] = xi[(size_t)base * DIM + idx];
    __syncthreads();
    for (int c = tid; c < 2 * QK_W + DIM; c += 256) {
        const float* W; float* O; int lc, ow;
        if (c < QK_W)            { W = wq; O = qo; lc = c;            ow = QK_W; }
        else if (c < 2 * QK_W)   { W = wk; O = ko; lc = c - QK_W;     ow = QK_W; }
        else                     { W = wv; O = vo; lc = c - 2 * QK_W; ow = DIM;  }
        float acc[16];
        #pragma unroll
        for (int n = 0; n < 16; n++) acc[n] = 0.0f;
        for (int kk = 0; kk < DIM; kk += 4) {
            float w0 = W[(kk + 0) * ow + lc];
            float w1 = W[(kk + 1) * ow + lc];
            float w2 = W[(kk + 2) * ow + lc];
            float w3 = W[(kk + 3) * ow + lc];
            #pragma unroll
            for (int n = 0; n < 16; n++) {
                const float4 xv = *(const float4*)&xs[n * DIM + kk];
                acc[n] += xv.x * w0 + xv.y * w1 + xv.z * w2 + xv.w * w3;
            }
        }
        #pragma unroll
        for (int n = 0; n < 16; n++) O[(size_t)(base + n) * ow + lc] = acc[n];
    }
}

// ---------------- edge kernel, layer 0 (ur = radial only) ----------------

__global__ __launch_bounds__(256) void k_edge0(const float* dist, const float* swit,
        const int* esrc, const int* edst, const float* q, const float* kb,
        const float* pw1, const float* pb1, const float* pw2, const float* pb2,
        float* aij) {
    __shared__ float spw1[RDIM * 32], spb1[32], spw2[32 * 16], spb2[16];
    int tid = threadIdx.x;
    for (int i = tid; i < RDIM * 32; i += 256) spw1[i] = pw1[i];
    for (int i = tid; i < 32 * 16; i += 256) spw2[i] = pw2[i];
    if (tid < 32) spb1[tid] = pb1[tid];
    if (tid < 16) spb2[tid] = pb2[tid];
    __syncthreads();
    int e = blockIdx.x * 256 + tid;
    if (e >= N_EDGES) return;
    float d = dist[e], swv = swit[e];
    int s = esrc[e], t_ = edst[e];
    const float sigma_inv = 15.0f / 4.2f;
    float ur[RDIM];
    #pragma unroll
    for (int i = 0; i < 16; i++) {
        float cc = 0.8f + (float)i * (4.2f / 15.0f);
        float u  = (d - cc) * sigma_inv;
        ur[i] = __expf(-u * u);
    }
    float wd[16];
    #pragma unroll
    for (int dd = 0; dd < 16; dd++) wd[dd] = spb2[dd];
    for (int j = 0; j < 32; j++) {
        float a = spb1[j];
        #pragma unroll
        for (int i = 0; i < 16; i++) a += ur[i] * spw1[i * 32 + j];
        float sj = a / (1.0f + __expf(-a));
        #pragma unroll
        for (int dd = 0; dd < 16; dd++) wd[dd] += sj * spw2[j * 16 + dd];
    }
    const float4* qr = (const float4*)(q  + (size_t)t_ * QK_W);
    const float4* kr = (const float4*)(kb + (size_t)s  * QK_W);
    float scale = swv * 0.25f;   // switch / sqrt(ATT)
    for (int h = 0; h < NH; h++) {
        float acc = 0.0f;
        #pragma unroll
        for (int i4 = 0; i4 < 4; i4++) {
            float4 qv = qr[h * 4 + i4];
            float4 kv = kr[h * 4 + i4];
            acc += qv.x * kv.x * wd[i4 * 4 + 0] + qv.y * kv.y * wd[i4 * 4 + 1]
                 + qv.z * kv.z * wd[i4 * 4 + 2] + qv.w * kv.w * wd[i4 * 4 + 3];
        }
        aij[(size_t)e * NH + h] = acc * scale;
    }
}

// ---------------- edge kernel, layer 1 (ur = [radial, us_l(th)]) ----------------

__global__ __launch_bounds__(256) void k_edge1(const float* dist, const float* swit,
        const int* esrc, const int* edst, const float* vec,
        const float* q, const float* kb, const float* Vi,
        const float* pw1, const float* pb1, const float* pw2, const float* pb2,
        float* aij) {
    __shared__ float spw1[32 * 32], spb1[32], spw2[32 * 16], spb2[16];
    int tid = threadIdx.x;
    for (int i = tid; i < 32 * 32; i += 256) spw1[i] = pw1[i];
    for (int i = tid; i < 32 * 16; i += 256) spw2[i] = pw2[i];
    if (tid < 32) spb1[tid] = pb1[tid];
    if (tid < 16) spb2[tid] = pb2[tid];
    __syncthreads();
    int e = blockIdx.x * 256 + tid;
    if (e >= N_EDGES) return;
    float d = dist[e], swv = swit[e];
    int s = esrc[e], t_ = edst[e];
    const float sigma_inv = 15.0f / 4.2f;
    float ur[32];
    #pragma unroll
    for (int i = 0; i < 16; i++) {
        float cc = 0.8f + (float)i * (4.2f / 15.0f);
        float u  = (d - cc) * sigma_inv;
        ur[i] = __expf(-u * u);
    }
    float invd = 1.0f / d;
    float vx = vec[(size_t)e * 3 + 0] * invd;
    float vy = vec[(size_t)e * 3 + 1] * invd;
    float vz = vec[(size_t)e * 3 + 2] * invd;
    float Y[16];
    sph16(vx, vy, vz, Y);
    const float par[16] = {1.f,-1.f,-1.f,-1.f,1.f,1.f,1.f,1.f,1.f,-1.f,-1.f,-1.f,-1.f,-1.f,-1.f,-1.f};
    const float* Vd = Vi + (size_t)t_ * 64;
    const float* Vs = Vi + (size_t)s  * 64;
    #pragma unroll
    for (int th = 0; th < THH; th++) {
        float us0 = 0, us1 = 0, us2 = 0, us3 = 0;
        #pragma unroll
        for (int m = 0; m < 16; m++) {
            float xv = (Vd[th * 16 + m] + par[m] * Vs[th * 16 + m]) * Y[m];
            if (m == 0)      us0 += xv;
            else if (m < 4)  us1 += xv;
            else if (m < 9)  us2 += xv;
            else             us3 += xv;
        }
        ur[16 + 0 * 4 + th] = us0;
        ur[16 + 1 * 4 + th] = us1;
        ur[16 + 2 * 4 + th] = us2;
        ur[16 + 3 * 4 + th] = us3;
    }
    float wd[16];
    #pragma unroll
    for (int dd = 0; dd < 16; dd++) wd[dd] = spb2[dd];
    for (int j = 0; j < 32; j++) {
        float a = spb1[j];
        #pragma unroll
        for (int i = 0; i < 32; i++) a += ur[i] * spw1[i * 32 + j];
        float sj = a / (1.0f + __expf(-a));
        #pragma unroll
        for (int dd = 0; dd < 16; dd++) wd[dd] += sj * spw2[j * 16 + dd];
    }
    const float4* qr = (const float4*)(q  + (size_t)t_ * QK_W);
    const float4* kr = (const float4*)(kb + (size_t)s  * QK_W);
    float scale = swv * 0.25f;
    for (int h = 0; h < NH; h++) {
        float acc = 0.0f;
        #pragma unroll
        for (int i4 = 0; i4 < 4; i4++) {
            float4 qv = qr[h * 4 + i4];
            float4 kv = kr[h * 4 + i4];
            acc += qv.x * kv.x * wd[i4 * 4 + 0] + qv.y * kv.y * wd[i4 * 4 + 1]
                 + qv.z * kv.z * wd[i4 * 4 + 2] + qv.w * kv.w * wd[i4 * 4 + 3];
        }
        aij[(size_t)e * NH + h] = acc * scale;
    }
}

// ---------------- aggregation, layer 0: mi and Vi ----------------

__global__ __launch_bounds__(256) void k_agg0(const int* off, const int* elist, const int* esrc,
        const float* dist, const float* vec, const float* aij, const float* vbuf,
        float* mi, float* Vi) {
    int n = blockIdx.x;
    int tid = threadIdx.x;
    int start = off[n], end = off[n + 1];
    float acc = 0.0f;
    if (tid < DIM) {
        int h = tid / VD;
        for (int i = start; i < end; i++) {
            int e = elist[i];
            int s = esrc[e];
            acc += aij[(size_t)e * NH + h] * vbuf[(size_t)s * DIM + tid];
        }
        mi[(size_t)n * DIM + tid] = acc;
    } else if (tid < DIM + 64) {
        int u = tid - DIM;
        int th = u >> 4, sm = u & 15;
        for (int i = start; i < end; i++) {
            int e = elist[i];
            float invd = 1.0f / dist[e];
            float vx = vec[(size_t)e * 3 + 0] * invd;
            float vy = vec[(size_t)e * 3 + 1] * invd;
            float vz = vec[(size_t)e * 3 + 2] * invd;
            float Y[16];
            sph16(vx, vy, vz, Y);
            acc += aij[(size_t)e * NH + SH_HEADS + th] * sel16(Y, sm);
        }
        Vi[(size_t)n * 64 + u] = acc;
    }
}

// ---------------- aggregation, layer 1: mi only ----------------

__global__ __launch_bounds__(256) void k_agg1(const int* off, const int* elist, const int* esrc,
        const float* aij, const float* vbuf, float* mi) {
    int n = blockIdx.x;
    int tid = threadIdx.x;
    if (tid >= DIM) return;
    int start = off[n], end = off[n + 1];
    int h = tid / VD;
    float acc = 0.0f;
    for (int i = start; i < end; i++) {
        int e = elist[i];
        int s = esrc[e];
        acc += aij[(size_t)e * NH + h] * vbuf[(size_t)s * DIM + tid];
    }
    mi[(size_t)n * DIM + tid] = acc;
}

// ---------------- update: xo = LN(xi + [xi,mi] @ uw + ub) ----------------

__global__ __launch_bounds__(256) void k_update(const float* xi, const float* mi,
        const float* uw, const float* ub, float* xo) {
    __shared__ float us_[16 * UI_W];
    __shared__ float yt[16 * DIM];
    __shared__ float red[256];
    __shared__ float mus[16], rstds[16];
    int base = blockIdx.x * 16;
    int tid  = threadIdx.x;
    for (int idx = tid; idx < 16 * UI_W; idx += 256) {
        int n = idx / UI_W, kk = idx - n * UI_W;
        us_[idx] = (kk < DIM) ? xi[(size_t)(base + n) * DIM + kk]
                              : mi[(size_t)(base + n) * DIM + (kk - DIM)];
    }
    __syncthreads();
    int c = tid;
    if (c < DIM) {
        float acc[16];
        #pragma unroll
        for (int n = 0; n < 16; n++) acc[n] = 0.0f;
        for (int kk = 0; kk < UI_W; kk += 4) {
            float w0 = uw[(kk + 0) * DIM + c];
            float w1 = uw[(kk + 1) * DIM + c];
            float w2 = uw[(kk + 2) * DIM + c];
            float w3 = uw[(kk + 3) * DIM + c];
            #pragma unroll
            for (int n = 0; n < 16; n++) {
                const float4 xv = *(const float4*)&us_[n * UI_W + kk];
                acc[n] += xv.x * w0 + xv.y * w1 + xv.z * w2 + xv.w * w3;
            }
        }
        float bb = ub[c];
        #pragma unroll
        for (int n = 0; n < 16; n++) yt[n * DIM + c] = us_[n * UI_W + c] + acc[n] + bb;
    }
    __syncthreads();
    { int n2 = tid >> 4, j = tid & 15;
      float s = 0.0f;
      for (int c2 = j; c2 < DIM; c2 += 16) s += yt[n2 * DIM + c2];
      red[tid] = s; }
    __syncthreads();
    if (tid < 16) { float s = 0; for (int j = 0; j < 16; j++) s += red[tid * 16 + j]; mus[tid] = s / (float)DIM; }
    __syncthreads();
    { int n2 = tid >> 4, j = tid & 15;
      float mu = mus[n2], s = 0.0f;
      for (int c2 = j; c2 < DIM; c2 += 16) { float d = yt[n2 * DIM + c2] - mu; s += d * d; }
      red[tid] = s; }
    __syncthreads();
    if (tid < 16) { float s = 0; for (int j = 0; j < 16; j++) s += red[tid * 16 + j]; rstds[tid] = rsqrtf(s / (float)DIM + 1e-6f); }
    __syncthreads();
    if (c < DIM) {
        #pragma unroll
        for (int n = 0; n < 16; n++)
            xo[(size_t)(base + n) * DIM + c] = (yt[n * DIM + c] - mus[n]) * rstds[n];
    }
}

// ---------------- launch ----------------

extern "C" void kernel_launch(void* const* d_in, const int* in_sizes, int n_in,
                              void* d_out, int out_size, void* d_ws, size_t ws_size,
                              hipStream_t stream) {
    const int*   species = (const int*)  d_in[0];
    const float* dist    = (const float*)d_in[1];
    const float* swit    = (const float*)d_in[2];
    const int*   esrc    = (const int*)  d_in[3];
    const int*   edst    = (const int*)  d_in[4];
    const float* vec     = (const float*)d_in[5];
    const float* z_table = (const float*)d_in[6];
    const float* wsp     = (const float*)d_in[7];
    const float* pw1_0 = (const float*)d_in[8],  *pb1_0 = (const float*)d_in[9];
    const float* pw2_0 = (const float*)d_in[10], *pb2_0 = (const float*)d_in[11];
    const float* wq0 = (const float*)d_in[12], *wk0 = (const float*)d_in[13];
    const float* wv0 = (const float*)d_in[14], *uw0 = (const float*)d_in[15];
    const float* ub0 = (const float*)d_in[16];
    const float* pw1_1 = (const float*)d_in[17], *pb1_1 = (const float*)d_in[18];
    const float* pw2_1 = (const float*)d_in[19], *pb2_1 = (const float*)d_in[20];
    const float* wq1 = (const float*)d_in[21], *wk1 = (const float*)d_in[22];
    const float* wv1 = (const float*)d_in[23], *uw1 = (const float*)d_in[24];
    const float* ub1 = (const float*)d_in[25];
    float* out = (float*)d_out;

    char* p = (char*)d_ws;
    auto alloc = [&](size_t bytes) -> char* {
        char* r = p;
        p += (bytes + 255) & ~(size_t)255;
        return r;
    };
    int* deg    = (int*)alloc((size_t)N_NODES * 4);
    int* off    = (int*)alloc((size_t)(N_NODES + 1) * 4);
    int* cursor = (int*)alloc((size_t)N_NODES * 4);
    int* elist  = (int*)alloc((size_t)N_EDGES * 4);
    float* xiA  = (float*)alloc((size_t)N_NODES * DIM * 4);
    float* xiB  = (float*)alloc((size_t)N_NODES * DIM * 4);
    float* qb   = (float*)alloc((size_t)N_NODES * QK_W * 4);
    float* kb   = (float*)alloc((size_t)N_NODES * QK_W * 4);
    float* vb   = (float*)alloc((size_t)N_NODES * DIM * 4);
    float* aij  = (float*)alloc((size_t)N_EDGES * NH * 4);
    float* Vi   = (float*)alloc((size_t)N_NODES * 64 * 4);
    float* mi   = (float*)alloc((size_t)N_NODES * DIM * 4);

    const int NB_N  = (N_NODES + 255) / 256;
    const int NB_E  = (N_EDGES + 255) / 256;
    const int NB_T  = N_NODES / 16;   // 625

    k_zero<<<NB_N, 256, 0, stream>>>(deg);
    k_deg<<<NB_E, 256, 0, stream>>>(edst, deg);
    k_scan<<<1, 1024, 0, stream>>>(deg, off, cursor);
    k_scatter<<<NB_E, 256, 0, stream>>>(edst, cursor, elist);

    k_node_init<<<NB_T, 256, 0, stream>>>(species, z_table, wsp, xiA);

    // layer 0
    k_qkv<<<NB_T, 256, 0, stream>>>(xiA, wq0, wk0, wv0, qb, kb, vb);
    k_edge0<<<NB_E, 256, 0, stream>>>(dist, swit, esrc, edst, qb, kb,
                                      pw1_0, pb1_0, pw2_0, pb2_0, aij);
    k_agg0<<<N_NODES, 256, 0, stream>>>(off, elist, esrc, dist, vec, aij, vb, mi, Vi);
    k_update<<<NB_T, 256, 0, stream>>>(xiA, mi, uw0, ub0, xiB);

    // layer 1
    k_qkv<<<NB_T, 256, 0, stream>>>(xiB, wq1, wk1, wv1, qb, kb, vb);
    k_edge1<<<NB_E, 256, 0, stream>>>(dist, swit, esrc, edst, vec, qb, kb, Vi,
                                      pw1_1, pb1_1, pw2_1, pb2_1, aij);
    k_agg1<<<N_NODES, 256, 0, stream>>>(off, elist, esrc, aij, vb, mi);
    k_update<<<NB_T, 256, 0, stream>>>(xiB, mi, uw1, ub1, out);
}